// Round 1
// baseline (2643.486 us; speedup 1.0000x reference)
//
#include <hip/hip_runtime.h>

// Sizes fixed by the problem
#define Bb   64
#define Ee   2048
#define Tt   64
#define Gg   4096
#define Ii   256
#define Hh   32
#define Dd   64

using f32x4_t  = __attribute__((ext_vector_type(4))) float;
using bf16x8_t = __attribute__((ext_vector_type(8))) __bf16;

__device__ __forceinline__ unsigned short f2bf(float f) {
  unsigned u = __float_as_uint(f);
  u += 0x7FFFu + ((u >> 16) & 1u);          // RNE
  return (unsigned short)(u >> 16);
}
__device__ __forceinline__ float ldkv(float v) { return v; }
__device__ __forceinline__ float ldkv(unsigned short v) {
  return __uint_as_float(((unsigned)v) << 16);
}

template <typename T> __device__ __forceinline__ float4 ld4(const T* p);
template <> __device__ __forceinline__ float4 ld4<float>(const float* p) {
  return *(const float4*)p;
}
template <> __device__ __forceinline__ float4 ld4<unsigned short>(const unsigned short* p) {
  ushort4 u = *(const ushort4*)p;
  return make_float4(ldkv(u.x), ldkv(u.y), ldkv(u.z), ldkv(u.w));
}

// ---------------- big memcpy: attention_state -> out ----------------
__global__ void copy_state_k(const float4* __restrict__ src, float4* __restrict__ dst, long n4) {
  long i = (long)blockIdx.x * blockDim.x + threadIdx.x;
  long stride = (long)gridDim.x * blockDim.x;
  for (; i < n4; i += stride) dst[i] = src[i];
}

// ---------------- fp32 -> bf16 convert ----------------
__global__ void conv_bf16_k(const float4* __restrict__ in, unsigned short* __restrict__ out, long n4) {
  long i = (long)blockIdx.x * blockDim.x + threadIdx.x;
  long stride = (long)gridDim.x * blockDim.x;
  for (; i < n4; i += stride) {
    float4 f = in[i];
    ushort4 u;
    u.x = f2bf(f.x); u.y = f2bf(f.y); u.z = f2bf(f.z); u.w = f2bf(f.w);
    *(ushort4*)(out + i * 4) = u;
  }
}

// ---------------- transpose + convert: W[K][N] fp32 -> Wt[N][K] bf16 ----------------
__global__ void transpose_bf16_k(const float* __restrict__ W, unsigned short* __restrict__ Wt,
                                 int K, int N) {
  __shared__ unsigned short tile[64][65];
  int k0 = blockIdx.x * 64, n0 = blockIdx.y * 64;
  int c = threadIdx.x & 63;       // column within tile
  int r4 = threadIdx.x >> 6;      // 0..3
  #pragma unroll
  for (int i = 0; i < 16; i++) {
    int r = r4 + i * 4;           // k-row within tile
    tile[r][c] = f2bf(W[(long)(k0 + r) * N + n0 + c]);
  }
  __syncthreads();
  #pragma unroll
  for (int i = 0; i < 16; i++) {
    int r = r4 + i * 4;           // n-row within tile
    Wt[(long)(n0 + r) * K + k0 + c] = tile[c][r];
  }
}

// ---------------- layer norm (optional scale/bias/residual) ----------------
__global__ void ln_k(const float* __restrict__ x, const float* __restrict__ scale,
                     const float* __restrict__ bias, const float* __restrict__ res,
                     float* __restrict__ y, int C) {
  int row = blockIdx.x;
  const float* xr = x + (long)row * C;
  float s = 0.f, s2 = 0.f;
  for (int c = threadIdx.x; c < C; c += blockDim.x) {
    float v = xr[c];
    s += v; s2 += v * v;
  }
  __shared__ float rs[8], rs2[8];
  int lane = threadIdx.x & 63, w = threadIdx.x >> 6;
  #pragma unroll
  for (int o = 32; o; o >>= 1) { s += __shfl_down(s, o, 64); s2 += __shfl_down(s2, o, 64); }
  if (lane == 0) { rs[w] = s; rs2[w] = s2; }
  __syncthreads();
  if (threadIdx.x == 0) {
    float ts = 0.f, ts2 = 0.f;
    int nw = blockDim.x >> 6;
    for (int i = 0; i < nw; i++) { ts += rs[i]; ts2 += rs2[i]; }
    float mu = ts / C;
    float var = ts2 / C - mu * mu;
    rs[0] = mu;
    rs2[0] = rsqrtf(var + 1e-6f);
  }
  __syncthreads();
  float mu = rs[0], rstd = rs2[0];
  for (int c = threadIdx.x; c < C; c += blockDim.x) {
    float v = (xr[c] - mu) * rstd;
    if (scale) v *= scale[c];
    if (bias)  v += bias[c];
    if (res)   v += res[(long)row * C + c];
    y[(long)row * C + c] = v;
  }
}

// ---------------- M=64 projection: Y[64][N] += X[64][K] @ W[K][N], split-K ----------------
__global__ __launch_bounds__(256)
void proj_k(const float* __restrict__ X, const float* __restrict__ W,
            float* __restrict__ Y, int K, int N) {
  int n  = blockIdx.x * 256 + threadIdx.x;
  int k0 = blockIdx.y * 128;
  float acc[64];
  #pragma unroll
  for (int m = 0; m < 64; m++) acc[m] = 0.f;
  for (int kk = 0; kk < 128; kk++) {
    int k = k0 + kk;
    float wv = W[(long)k * N + n];
    #pragma unroll
    for (int m = 0; m < 64; m++) acc[m] += X[m * K + k] * wv;  // X load is wave-uniform -> s_load
  }
  #pragma unroll
  for (int m = 0; m < 64; m++) unsafeAtomicAdd(&Y[(long)m * N + n], acc[m]);
}

// ---------------- KV-cache update at token_index ----------------
__global__ void update_state_k(float* __restrict__ st, const float* __restrict__ kb,
                               const float* __restrict__ vb, const int* __restrict__ tokp) {
  int t = *tokp;
  int idx = blockIdx.x * 256 + threadIdx.x;     // 64*2048
  if (idx >= Bb * Ee) return;
  int b = idx >> 11, e = idx & 2047;
  st[((long)b * Ii + t) * Ee + e]          = kb[idx];
  st[((long)(b + Bb) * Ii + t) * Ee + e]   = vb[idx];
}

// ---------------- attention (Q=1 per batch): one wave per (b,h) ----------------
template <typename KVT>
__global__ void attn_k(const float* __restrict__ Q, const KVT* __restrict__ Kc,
                       const KVT* __restrict__ Vc, float* __restrict__ O,
                       const int* __restrict__ tokp, const int* __restrict__ maskp,
                       int L, long bstride, float scale) {
  int b = blockIdx.x, h = blockIdx.y;
  int lane = threadIdx.x;                       // 64 threads = 1 wave
  __shared__ float sc[256];
  const float* qp = Q + (long)b * Ee + h * Dd;  // wave-uniform -> SGPRs
  int valid_until = tokp ? (*tokp + 1) : L;

  float mx = -3.0e38f;
  for (int pos = lane; pos < L; pos += 64) {
    bool valid = maskp ? (maskp[(long)b * L + pos] != 0) : (pos < valid_until);
    float s = -1.0e30f;
    if (valid) {
      const KVT* kr = Kc + (long)b * bstride + (long)pos * Ee + h * Dd;
      float acc = 0.f;
      #pragma unroll
      for (int j = 0; j < 16; j++) {
        float4 kv = ld4(kr + j * 4);
        acc += qp[j*4+0]*kv.x + qp[j*4+1]*kv.y + qp[j*4+2]*kv.z + qp[j*4+3]*kv.w;
      }
      s = acc * scale;
    }
    sc[pos] = s;
    mx = fmaxf(mx, s);
  }
  __syncthreads();
  #pragma unroll
  for (int o = 32; o; o >>= 1) mx = fmaxf(mx, __shfl_down(mx, o, 64));
  mx = __shfl(mx, 0, 64);

  float sum = 0.f;
  for (int pos = lane; pos < L; pos += 64) {
    float e = expf(sc[pos] - mx);
    sc[pos] = e;
    sum += e;
  }
  __syncthreads();
  #pragma unroll
  for (int o = 32; o; o >>= 1) sum += __shfl_down(sum, o, 64);
  sum = __shfl(sum, 0, 64);
  float inv = 1.0f / sum;

  float acc = 0.f;
  for (int pos = 0; pos < L; pos++) {
    float wgt = sc[pos];
    if (wgt != 0.0f)
      acc += wgt * ldkv(Vc[(long)b * bstride + (long)pos * Ee + h * Dd + lane]);
  }
  O[(long)b * Ee + h * Dd + lane] = acc * inv;
}

// ---------------- bf16 MFMA GEMM: C[M][N] = A[M][K] @ B (Bt is [N][K]) ----------------
__global__ __launch_bounds__(256)
void gemm_bf16_k(const unsigned short* __restrict__ A, const unsigned short* __restrict__ Bt,
                 unsigned short* __restrict__ C, int M, int N, int K) {
  __shared__ unsigned short As[128 * 32];
  __shared__ unsigned short Bs[128 * 32];
  const int m0 = blockIdx.x * 128;
  const int n0 = blockIdx.y * 128;
  const int tid  = threadIdx.x;
  const int lane = tid & 63;
  const int wave = tid >> 6;
  const int wm = (wave >> 1) * 64;
  const int wn = (wave & 1) * 64;
  const int fr = lane & 15;
  const int fq = lane >> 4;

  const int r0 = tid >> 2;            // staging row 0..63
  const int g0 = tid & 3;             // k-group 0..3
  const int so1 = r0 * 32 + ((g0 ^ ((r0 >> 1) & 3)) * 8);   // XOR swizzle (2-way max)
  const int so2 = so1 + 64 * 32;

  f32x4_t acc[4][4];
  const f32x4_t zero = {0.f, 0.f, 0.f, 0.f};
  #pragma unroll
  for (int i = 0; i < 4; i++)
    #pragma unroll
    for (int j = 0; j < 4; j++) acc[i][j] = zero;

  const long aR1 = (long)(m0 + r0) * K;
  const long aR2 = (long)(m0 + r0 + 64) * K;
  const long bR1 = (long)(n0 + r0) * K;
  const long bR2 = (long)(n0 + r0 + 64) * K;

  for (int k0 = 0; k0 < K; k0 += 32) {
    uint4 va1 = *(const uint4*)(A  + aR1 + k0 + g0 * 8);
    uint4 va2 = *(const uint4*)(A  + aR2 + k0 + g0 * 8);
    uint4 vb1 = *(const uint4*)(Bt + bR1 + k0 + g0 * 8);
    uint4 vb2 = *(const uint4*)(Bt + bR2 + k0 + g0 * 8);
    __syncthreads();
    *(uint4*)(As + so1) = va1;
    *(uint4*)(As + so2) = va2;
    *(uint4*)(Bs + so1) = vb1;
    *(uint4*)(Bs + so2) = vb2;
    __syncthreads();

    bf16x8_t af[4], bb[4];
    #pragma unroll
    for (int ms = 0; ms < 4; ms++) {
      int row = wm + ms * 16 + fr;
      af[ms] = __builtin_bit_cast(bf16x8_t,
               *(const uint4*)(As + row * 32 + ((fq ^ ((row >> 1) & 3)) * 8)));
    }
    #pragma unroll
    for (int ns = 0; ns < 4; ns++) {
      int row = wn + ns * 16 + fr;
      bb[ns] = __builtin_bit_cast(bf16x8_t,
               *(const uint4*)(Bs + row * 32 + ((fq ^ ((row >> 1) & 3)) * 8)));
    }
    #pragma unroll
    for (int ms = 0; ms < 4; ms++)
      #pragma unroll
      for (int ns = 0; ns < 4; ns++)
        acc[ms][ns] = __builtin_amdgcn_mfma_f32_16x16x32_bf16(af[ms], bb[ns], acc[ms][ns], 0, 0, 0);
  }

  // epilogue: C/D layout col=lane&15, row=quad*4+reg
  #pragma unroll
  for (int ms = 0; ms < 4; ms++) {
    #pragma unroll
    for (int ns = 0; ns < 4; ns++) {
      int row = m0 + wm + ms * 16 + fq * 4;
      int col = n0 + wn + ns * 16 + fr;
      #pragma unroll
      for (int r = 0; r < 4; r++)
        C[(long)(row + r) * N + col] = f2bf(acc[ms][ns][r]);
    }
  }
}

// ---------------- elementwise ----------------
__global__ void gelu_mul_k(const float* __restrict__ w, const float* __restrict__ v,
                           float* __restrict__ out, int n) {
  int i = blockIdx.x * 256 + threadIdx.x;
  if (i < n) {
    float x = w[i];
    out[i] = 0.5f * x * (1.0f + erff(x * 0.70710678118654752f)) * v[i];
  }
}
__global__ void add_k(const float* __restrict__ a, const float* __restrict__ b,
                      float* __restrict__ out, int n) {
  int i = blockIdx.x * 256 + threadIdx.x;
  if (i < n) out[i] = a[i] + b[i];
}

extern "C" void kernel_launch(void* const* d_in, const int* in_sizes, int n_in,
                              void* d_out, int out_size, void* d_ws, size_t ws_size,
                              hipStream_t stream) {
  const float* dec    = (const float*)d_in[0];
  const float* enc    = (const float*)d_in[1];
  const float* astate = (const float*)d_in[2];
  const int*   amask  = (const int*)d_in[3];
  const int*   tokp   = (const int*)d_in[4];
  const float* ln_pre_sa_b = (const float*)d_in[5];
  const float* q_sa = (const float*)d_in[6];
  const float* k_sa = (const float*)d_in[7];
  const float* v_sa = (const float*)d_in[8];
  const float* o_sa = (const float*)d_in[9];
  const float* ln_sa_s = (const float*)d_in[10];
  const float* ln_sa_b = (const float*)d_in[11];
  const float* ln_pre_ca_b = (const float*)d_in[12];
  const float* q_ca = (const float*)d_in[13];
  const float* k_ca = (const float*)d_in[14];
  const float* v_ca = (const float*)d_in[15];
  const float* o_ca = (const float*)d_in[16];
  const float* ln_ca_s = (const float*)d_in[17];
  const float* ln_ca_b = (const float*)d_in[18];
  const float* glu_ln0_b = (const float*)d_in[19];
  const float* fc0 = (const float*)d_in[20];
  const float* fc1 = (const float*)d_in[21];
  const float* glu_ln1_s = (const float*)d_in[22];
  const float* glu_ln1_b = (const float*)d_in[23];
  const float* fc2 = (const float*)d_in[24];

  float* out_dec   = (float*)d_out;
  float* out_state = out_dec + (long)Bb * Ee;        // 128*256*2048 floats

  // ---- workspace carve (all offsets 256B-aligned by construction) ----
  // zero zone first (atomic-accumulated projection outputs)
  float* qb  = (float*)d_ws;            // 64*2048
  float* kb  = qb  + 131072;
  float* vb  = kb  + 131072;
  float* ob  = vb  + 131072;
  float* q2  = ob  + 131072;
  float* ob2 = q2  + 131072;
  float* z2  = ob2 + 131072;
  float* w0  = z2  + 131072;            // 64*4096
  float* v1  = w0  + 262144;
  size_t zero_bytes = (7L * 131072 + 2L * 262144) * 4;   // 5,767,168 B
  float* x1  = v1  + 262144;
  float* ab  = x1  + 131072;
  float* ds2 = ab  + 131072;
  float* x3  = ds2 + 131072;
  float* cb  = x3  + 131072;
  float* ds3 = cb  + 131072;
  float* zb  = ds3 + 131072;
  float* wv  = zb  + 131072;            // 64*4096
  float* wvn = wv  + 262144;
  unsigned short* ebf = (unsigned short*)(wvn + 262144);  // 4096*2048 bf16
  unsigned short* kt  = ebf + 8388608;                    // 2048*2048 bf16 (transposed)
  unsigned short* vt  = kt  + 4194304;
  unsigned short* ekb = vt  + 4194304;                    // 4096*2048 bf16
  unsigned short* evb = ekb + 8388608;                    // total ~78.6 MB

  hipMemsetAsync(d_ws, 0, zero_bytes, stream);

  // full attention_state copy to output (the structural 536 MB)
  copy_state_k<<<4096, 256, 0, stream>>>((const float4*)astate, (float4*)out_state,
                                         (long)128 * Ii * Ee / 4);

  // bf16 conversions for the big cross-attn GEMMs
  conv_bf16_k<<<2048, 256, 0, stream>>>((const float4*)enc, ebf, (long)Bb * Tt * Ee / 4);
  transpose_bf16_k<<<dim3(32, 32), 256, 0, stream>>>(k_ca, kt, Ee, Ee);
  transpose_bf16_k<<<dim3(32, 32), 256, 0, stream>>>(v_ca, vt, Ee, Ee);

  // ek = enc @ k_ca ; ev = enc @ v_ca   (M=4096, N=2048, K=2048, bf16 MFMA)
  gemm_bf16_k<<<dim3(32, 16), 256, 0, stream>>>(ebf, kt, ekb, 4096, Ee, Ee);
  gemm_bf16_k<<<dim3(32, 16), 256, 0, stream>>>(ebf, vt, evb, 4096, Ee, Ee);

  // --- self-attention block ---
  ln_k<<<Bb, 256, 0, stream>>>(dec, nullptr, ln_pre_sa_b, nullptr, x1, Ee);
  proj_k<<<dim3(8, 16), 256, 0, stream>>>(x1, q_sa, qb, Ee, Ee);
  proj_k<<<dim3(8, 16), 256, 0, stream>>>(x1, k_sa, kb, Ee, Ee);
  proj_k<<<dim3(8, 16), 256, 0, stream>>>(x1, v_sa, vb, Ee, Ee);
  update_state_k<<<512, 256, 0, stream>>>(out_state, kb, vb, tokp);
  attn_k<float><<<dim3(Bb, Hh), 64, 0, stream>>>(qb, out_state,
      out_state + (long)Bb * Ii * Ee, ab, tokp, nullptr, Ii, (long)Ii * Ee, 0.125f);
  proj_k<<<dim3(8, 16), 256, 0, stream>>>(ab, o_sa, ob, Ee, Ee);
  ln_k<<<Bb, 256, 0, stream>>>(ob, ln_sa_s, ln_sa_b, dec, ds2, Ee);

  // --- cross-attention block ---
  ln_k<<<Bb, 256, 0, stream>>>(ds2, nullptr, ln_pre_ca_b, nullptr, x3, Ee);
  proj_k<<<dim3(8, 16), 256, 0, stream>>>(x3, q_ca, q2, Ee, Ee);
  attn_k<unsigned short><<<dim3(Bb, Hh), 64, 0, stream>>>(q2, ekb, evb, cb,
      nullptr, amask, Tt, (long)Tt * Ee, 0.125f);
  proj_k<<<dim3(8, 16), 256, 0, stream>>>(cb, o_ca, ob2, Ee, Ee);
  ln_k<<<Bb, 256, 0, stream>>>(ob2, ln_ca_s, ln_ca_b, ds2, ds3, Ee);

  // --- GLU block ---
  ln_k<<<Bb, 256, 0, stream>>>(ds3, nullptr, glu_ln0_b, nullptr, zb, Ee);
  proj_k<<<dim3(16, 16), 256, 0, stream>>>(zb, fc0, w0, Ee, Gg);
  proj_k<<<dim3(16, 16), 256, 0, stream>>>(zb, fc1, v1, Ee, Gg);
  gelu_mul_k<<<1024, 256, 0, stream>>>(w0, v1, wv, Bb * Gg);
  ln_k<<<Bb, 256, 0, stream>>>(wv, glu_ln1_s, glu_ln1_b, nullptr, wvn, Gg);
  proj_k<<<dim3(8, 32), 256, 0, stream>>>(wvn, fc2, z2, Gg, Ee);
  add_k<<<512, 256, 0, stream>>>(ds3, z2, out_dec, Bb * Ee);
}

// Round 2
// 1449.332 us; speedup vs baseline: 1.8239x; 1.8239x over previous
//
#include <hip/hip_runtime.h>

// Sizes fixed by the problem
#define Bb   64
#define Ee   2048
#define Tt   64
#define Gg   4096
#define Ii   256
#define Hh   32
#define Dd   64

using f32x4_t  = __attribute__((ext_vector_type(4))) float;
using bf16x8_t = __attribute__((ext_vector_type(8))) __bf16;

__device__ __forceinline__ unsigned short f2bf(float f) {
  unsigned u = __float_as_uint(f);
  u += 0x7FFFu + ((u >> 16) & 1u);          // RNE
  return (unsigned short)(u >> 16);
}
__device__ __forceinline__ float ldkv(float v) { return v; }
__device__ __forceinline__ float ldkv(unsigned short v) {
  return __uint_as_float(((unsigned)v) << 16);
}

template <typename T> __device__ __forceinline__ float4 ld4(const T* p);
template <> __device__ __forceinline__ float4 ld4<float>(const float* p) {
  return *(const float4*)p;
}
template <> __device__ __forceinline__ float4 ld4<unsigned short>(const unsigned short* p) {
  ushort4 u = *(const ushort4*)p;
  return make_float4(ldkv(u.x), ldkv(u.y), ldkv(u.z), ldkv(u.w));
}

// ---------------- big memcpy: attention_state -> out ----------------
__global__ void copy_state_k(const float4* __restrict__ src, float4* __restrict__ dst, long n4) {
  long i = (long)blockIdx.x * blockDim.x + threadIdx.x;
  long stride = (long)gridDim.x * blockDim.x;
  for (; i < n4; i += stride) dst[i] = src[i];
}

// ---------------- fp32 -> bf16 convert ----------------
__global__ void conv_bf16_k(const float4* __restrict__ in, unsigned short* __restrict__ out, long n4) {
  long i = (long)blockIdx.x * blockDim.x + threadIdx.x;
  long stride = (long)gridDim.x * blockDim.x;
  for (; i < n4; i += stride) {
    float4 f = in[i];
    ushort4 u;
    u.x = f2bf(f.x); u.y = f2bf(f.y); u.z = f2bf(f.z); u.w = f2bf(f.w);
    *(ushort4*)(out + i * 4) = u;
  }
}

// ---------------- transpose + convert: W[K][N] fp32 -> Wt[N][K] bf16 ----------------
__global__ void transpose_bf16_k(const float* __restrict__ W, unsigned short* __restrict__ Wt,
                                 int K, int N) {
  __shared__ unsigned short tile[64][65];
  int k0 = blockIdx.x * 64, n0 = blockIdx.y * 64;
  int c = threadIdx.x & 63;       // column within tile
  int r4 = threadIdx.x >> 6;      // 0..3
  #pragma unroll
  for (int i = 0; i < 16; i++) {
    int r = r4 + i * 4;           // k-row within tile
    tile[r][c] = f2bf(W[(long)(k0 + r) * N + n0 + c]);
  }
  __syncthreads();
  #pragma unroll
  for (int i = 0; i < 16; i++) {
    int r = r4 + i * 4;           // n-row within tile
    Wt[(long)(n0 + r) * K + k0 + c] = tile[c][r];
  }
}

// ---------------- layer norm (optional scale/bias/residual) ----------------
__global__ void ln_k(const float* __restrict__ x, const float* __restrict__ scale,
                     const float* __restrict__ bias, const float* __restrict__ res,
                     float* __restrict__ y, int C) {
  int row = blockIdx.x;
  const float* xr = x + (long)row * C;
  float s = 0.f, s2 = 0.f;
  for (int c = threadIdx.x; c < C; c += blockDim.x) {
    float v = xr[c];
    s += v; s2 += v * v;
  }
  __shared__ float rs[8], rs2[8];
  int lane = threadIdx.x & 63, w = threadIdx.x >> 6;
  #pragma unroll
  for (int o = 32; o; o >>= 1) { s += __shfl_down(s, o, 64); s2 += __shfl_down(s2, o, 64); }
  if (lane == 0) { rs[w] = s; rs2[w] = s2; }
  __syncthreads();
  if (threadIdx.x == 0) {
    float ts = 0.f, ts2 = 0.f;
    int nw = blockDim.x >> 6;
    for (int i = 0; i < nw; i++) { ts += rs[i]; ts2 += rs2[i]; }
    float mu = ts / C;
    float var = ts2 / C - mu * mu;
    rs[0] = mu;
    rs2[0] = rsqrtf(var + 1e-6f);
  }
  __syncthreads();
  float mu = rs[0], rstd = rs2[0];
  for (int c = threadIdx.x; c < C; c += blockDim.x) {
    float v = (xr[c] - mu) * rstd;
    if (scale) v *= scale[c];
    if (bias)  v += bias[c];
    if (res)   v += res[(long)row * C + c];
    y[(long)row * C + c] = v;
  }
}

// ---------------- M=64 projection: Y[64][N] += X[64][K] @ W[K][N] ----------------
// block = 256 threads: 32 n-quads (128 cols) x 8 m-groups (8 rows each = all 64 m)
// grid = (N/128, K/128); each block owns a 128-deep K-chunk; split-K via atomics.
// X tile (64 x 64 fp32 = 16 KB) staged in LDS; reads are 2-way broadcast (free).
// acc as f32x4_t[8] fully unrolled -> stays in VGPRs (the round-0 bug was acc[64]
// demoted to scratch: VGPR_Count=36, VALUBusy=2.5%).
__global__ __launch_bounds__(256)
void proj_k(const float* __restrict__ X, const float* __restrict__ W,
            float* __restrict__ Y, int K, int N) {
  __shared__ float Xs[64 * 64];
  const int nq = threadIdx.x & 31;          // n-quad index
  const int m0 = (threadIdx.x >> 5) * 8;    // first m of this thread's 8 rows
  const int n  = blockIdx.x * 128 + nq * 4;
  const int kbase = blockIdx.y * 128;

  f32x4_t acc[8];
  #pragma unroll
  for (int i = 0; i < 8; i++) acc[i] = (f32x4_t){0.f, 0.f, 0.f, 0.f};

  for (int k0 = kbase; k0 < kbase + 128; k0 += 64) {
    __syncthreads();
    #pragma unroll
    for (int j = 0; j < 16; j++) {
      int e = threadIdx.x + j * 256;        // e = m*64 + kk
      Xs[e] = X[(long)(e >> 6) * K + k0 + (e & 63)];
    }
    __syncthreads();
    #pragma unroll 4
    for (int kk = 0; kk < 64; kk++) {
      f32x4_t w4 = *(const f32x4_t*)(W + (long)(k0 + kk) * N + n);
      #pragma unroll
      for (int i = 0; i < 8; i++) {
        float xm = Xs[(m0 + i) * 64 + kk];
        acc[i] += xm * w4;
      }
    }
  }
  #pragma unroll
  for (int i = 0; i < 8; i++) {
    float* yp = Y + (long)(m0 + i) * N + n;
    unsafeAtomicAdd(yp + 0, acc[i][0]);
    unsafeAtomicAdd(yp + 1, acc[i][1]);
    unsafeAtomicAdd(yp + 2, acc[i][2]);
    unsafeAtomicAdd(yp + 3, acc[i][3]);
  }
}

// ---------------- KV-cache update at token_index ----------------
__global__ void update_state_k(float* __restrict__ st, const float* __restrict__ kb,
                               const float* __restrict__ vb, const int* __restrict__ tokp) {
  int t = *tokp;
  int idx = blockIdx.x * 256 + threadIdx.x;     // 64*2048
  if (idx >= Bb * Ee) return;
  int b = idx >> 11, e = idx & 2047;
  st[((long)b * Ii + t) * Ee + e]          = kb[idx];
  st[((long)(b + Bb) * Ii + t) * Ee + e]   = vb[idx];
}

// ---------------- attention (Q=1 per batch): one wave per (b,h) ----------------
template <typename KVT>
__global__ void attn_k(const float* __restrict__ Q, const KVT* __restrict__ Kc,
                       const KVT* __restrict__ Vc, float* __restrict__ O,
                       const int* __restrict__ tokp, const int* __restrict__ maskp,
                       int L, long bstride, float scale) {
  int b = blockIdx.x, h = blockIdx.y;
  int lane = threadIdx.x;                       // 64 threads = 1 wave
  __shared__ float sc[256];
  const float* qp = Q + (long)b * Ee + h * Dd;  // wave-uniform -> SGPRs
  int valid_until = tokp ? (*tokp + 1) : L;

  float mx = -3.0e38f;
  for (int pos = lane; pos < L; pos += 64) {
    bool valid = maskp ? (maskp[(long)b * L + pos] != 0) : (pos < valid_until);
    float s = -1.0e30f;
    if (valid) {
      const KVT* kr = Kc + (long)b * bstride + (long)pos * Ee + h * Dd;
      float acc = 0.f;
      #pragma unroll
      for (int j = 0; j < 16; j++) {
        float4 kv = ld4(kr + j * 4);
        acc += qp[j*4+0]*kv.x + qp[j*4+1]*kv.y + qp[j*4+2]*kv.z + qp[j*4+3]*kv.w;
      }
      s = acc * scale;
    }
    sc[pos] = s;
    mx = fmaxf(mx, s);
  }
  __syncthreads();
  #pragma unroll
  for (int o = 32; o; o >>= 1) mx = fmaxf(mx, __shfl_down(mx, o, 64));
  mx = __shfl(mx, 0, 64);

  float sum = 0.f;
  for (int pos = lane; pos < L; pos += 64) {
    float e = expf(sc[pos] - mx);
    sc[pos] = e;
    sum += e;
  }
  __syncthreads();
  #pragma unroll
  for (int o = 32; o; o >>= 1) sum += __shfl_down(sum, o, 64);
  sum = __shfl(sum, 0, 64);
  float inv = 1.0f / sum;

  float acc = 0.f;
  for (int pos = 0; pos < L; pos++) {
    float wgt = sc[pos];
    if (wgt != 0.0f)
      acc += wgt * ldkv(Vc[(long)b * bstride + (long)pos * Ee + h * Dd + lane]);
  }
  O[(long)b * Ee + h * Dd + lane] = acc * inv;
}

// ---------------- bf16 MFMA GEMM: C[M][N] = A[M][K] @ B (Bt is [N][K]) ----------------
__global__ __launch_bounds__(256)
void gemm_bf16_k(const unsigned short* __restrict__ A, const unsigned short* __restrict__ Bt,
                 unsigned short* __restrict__ C, int M, int N, int K) {
  __shared__ unsigned short As[128 * 32];
  __shared__ unsigned short Bs[128 * 32];
  const int m0 = blockIdx.x * 128;
  const int n0 = blockIdx.y * 128;
  const int tid  = threadIdx.x;
  const int lane = tid & 63;
  const int wave = tid >> 6;
  const int wm = (wave >> 1) * 64;
  const int wn = (wave & 1) * 64;
  const int fr = lane & 15;
  const int fq = lane >> 4;

  const int r0 = tid >> 2;            // staging row 0..63
  const int g0 = tid & 3;             // k-group 0..3
  const int so1 = r0 * 32 + ((g0 ^ ((r0 >> 1) & 3)) * 8);   // XOR swizzle (2-way max)
  const int so2 = so1 + 64 * 32;

  f32x4_t acc[4][4];
  const f32x4_t zero = {0.f, 0.f, 0.f, 0.f};
  #pragma unroll
  for (int i = 0; i < 4; i++)
    #pragma unroll
    for (int j = 0; j < 4; j++) acc[i][j] = zero;

  const long aR1 = (long)(m0 + r0) * K;
  const long aR2 = (long)(m0 + r0 + 64) * K;
  const long bR1 = (long)(n0 + r0) * K;
  const long bR2 = (long)(n0 + r0 + 64) * K;

  for (int k0 = 0; k0 < K; k0 += 32) {
    uint4 va1 = *(const uint4*)(A  + aR1 + k0 + g0 * 8);
    uint4 va2 = *(const uint4*)(A  + aR2 + k0 + g0 * 8);
    uint4 vb1 = *(const uint4*)(Bt + bR1 + k0 + g0 * 8);
    uint4 vb2 = *(const uint4*)(Bt + bR2 + k0 + g0 * 8);
    __syncthreads();
    *(uint4*)(As + so1) = va1;
    *(uint4*)(As + so2) = va2;
    *(uint4*)(Bs + so1) = vb1;
    *(uint4*)(Bs + so2) = vb2;
    __syncthreads();

    bf16x8_t af[4], bb[4];
    #pragma unroll
    for (int ms = 0; ms < 4; ms++) {
      int row = wm + ms * 16 + fr;
      af[ms] = __builtin_bit_cast(bf16x8_t,
               *(const uint4*)(As + row * 32 + ((fq ^ ((row >> 1) & 3)) * 8)));
    }
    #pragma unroll
    for (int ns = 0; ns < 4; ns++) {
      int row = wn + ns * 16 + fr;
      bb[ns] = __builtin_bit_cast(bf16x8_t,
               *(const uint4*)(Bs + row * 32 + ((fq ^ ((row >> 1) & 3)) * 8)));
    }
    #pragma unroll
    for (int ms = 0; ms < 4; ms++)
      #pragma unroll
      for (int ns = 0; ns < 4; ns++)
        acc[ms][ns] = __builtin_amdgcn_mfma_f32_16x16x32_bf16(af[ms], bb[ns], acc[ms][ns], 0, 0, 0);
  }

  // epilogue: C/D layout col=lane&15, row=quad*4+reg
  #pragma unroll
  for (int ms = 0; ms < 4; ms++) {
    #pragma unroll
    for (int ns = 0; ns < 4; ns++) {
      int row = m0 + wm + ms * 16 + fq * 4;
      int col = n0 + wn + ns * 16 + fr;
      #pragma unroll
      for (int r = 0; r < 4; r++)
        C[(long)(row + r) * N + col] = f2bf(acc[ms][ns][r]);
    }
  }
}

// ---------------- elementwise ----------------
__global__ void gelu_mul_k(const float* __restrict__ w, const float* __restrict__ v,
                           float* __restrict__ out, int n) {
  int i = blockIdx.x * 256 + threadIdx.x;
  if (i < n) {
    float x = w[i];
    out[i] = 0.5f * x * (1.0f + erff(x * 0.70710678118654752f)) * v[i];
  }
}
__global__ void add_k(const float* __restrict__ a, const float* __restrict__ b,
                      float* __restrict__ out, int n) {
  int i = blockIdx.x * 256 + threadIdx.x;
  if (i < n) out[i] = a[i] + b[i];
}

extern "C" void kernel_launch(void* const* d_in, const int* in_sizes, int n_in,
                              void* d_out, int out_size, void* d_ws, size_t ws_size,
                              hipStream_t stream) {
  const float* dec    = (const float*)d_in[0];
  const float* enc    = (const float*)d_in[1];
  const float* astate = (const float*)d_in[2];
  const int*   amask  = (const int*)d_in[3];
  const int*   tokp   = (const int*)d_in[4];
  const float* ln_pre_sa_b = (const float*)d_in[5];
  const float* q_sa = (const float*)d_in[6];
  const float* k_sa = (const float*)d_in[7];
  const float* v_sa = (const float*)d_in[8];
  const float* o_sa = (const float*)d_in[9];
  const float* ln_sa_s = (const float*)d_in[10];
  const float* ln_sa_b = (const float*)d_in[11];
  const float* ln_pre_ca_b = (const float*)d_in[12];
  const float* q_ca = (const float*)d_in[13];
  const float* k_ca = (const float*)d_in[14];
  const float* v_ca = (const float*)d_in[15];
  const float* o_ca = (const float*)d_in[16];
  const float* ln_ca_s = (const float*)d_in[17];
  const float* ln_ca_b = (const float*)d_in[18];
  const float* glu_ln0_b = (const float*)d_in[19];
  const float* fc0 = (const float*)d_in[20];
  const float* fc1 = (const float*)d_in[21];
  const float* glu_ln1_s = (const float*)d_in[22];
  const float* glu_ln1_b = (const float*)d_in[23];
  const float* fc2 = (const float*)d_in[24];

  float* out_dec   = (float*)d_out;
  float* out_state = out_dec + (long)Bb * Ee;        // 128*256*2048 floats

  // ---- workspace carve (all offsets 256B-aligned by construction) ----
  // zero zone first (atomic-accumulated projection outputs)
  float* qb  = (float*)d_ws;            // 64*2048
  float* kb  = qb  + 131072;
  float* vb  = kb  + 131072;
  float* ob  = vb  + 131072;
  float* q2  = ob  + 131072;
  float* ob2 = q2  + 131072;
  float* z2  = ob2 + 131072;
  float* w0  = z2  + 131072;            // 64*4096
  float* v1  = w0  + 262144;
  size_t zero_bytes = (7L * 131072 + 2L * 262144) * 4;   // 5,767,168 B
  float* x1  = v1  + 262144;
  float* ab  = x1  + 131072;
  float* ds2 = ab  + 131072;
  float* x3  = ds2 + 131072;
  float* cb  = x3  + 131072;
  float* ds3 = cb  + 131072;
  float* zb  = ds3 + 131072;
  float* wv  = zb  + 131072;            // 64*4096
  float* wvn = wv  + 262144;
  unsigned short* ebf = (unsigned short*)(wvn + 262144);  // 4096*2048 bf16
  unsigned short* kt  = ebf + 8388608;                    // 2048*2048 bf16 (transposed)
  unsigned short* vt  = kt  + 4194304;
  unsigned short* ekb = vt  + 4194304;                    // 4096*2048 bf16
  unsigned short* evb = ekb + 8388608;                    // total ~78.6 MB

  hipMemsetAsync(d_ws, 0, zero_bytes, stream);

  // full attention_state copy to output (the structural 536 MB)
  copy_state_k<<<4096, 256, 0, stream>>>((const float4*)astate, (float4*)out_state,
                                         (long)128 * Ii * Ee / 4);

  // bf16 conversions for the big cross-attn GEMMs
  conv_bf16_k<<<2048, 256, 0, stream>>>((const float4*)enc, ebf, (long)Bb * Tt * Ee / 4);
  transpose_bf16_k<<<dim3(32, 32), 256, 0, stream>>>(k_ca, kt, Ee, Ee);
  transpose_bf16_k<<<dim3(32, 32), 256, 0, stream>>>(v_ca, vt, Ee, Ee);

  // ek = enc @ k_ca ; ev = enc @ v_ca   (M=4096, N=2048, K=2048, bf16 MFMA)
  gemm_bf16_k<<<dim3(32, 16), 256, 0, stream>>>(ebf, kt, ekb, 4096, Ee, Ee);
  gemm_bf16_k<<<dim3(32, 16), 256, 0, stream>>>(ebf, vt, evb, 4096, Ee, Ee);

  // --- self-attention block ---
  ln_k<<<Bb, 256, 0, stream>>>(dec, nullptr, ln_pre_sa_b, nullptr, x1, Ee);
  proj_k<<<dim3(16, 16), 256, 0, stream>>>(x1, q_sa, qb, Ee, Ee);
  proj_k<<<dim3(16, 16), 256, 0, stream>>>(x1, k_sa, kb, Ee, Ee);
  proj_k<<<dim3(16, 16), 256, 0, stream>>>(x1, v_sa, vb, Ee, Ee);
  update_state_k<<<512, 256, 0, stream>>>(out_state, kb, vb, tokp);
  attn_k<float><<<dim3(Bb, Hh), 64, 0, stream>>>(qb, out_state,
      out_state + (long)Bb * Ii * Ee, ab, tokp, nullptr, Ii, (long)Ii * Ee, 0.125f);
  proj_k<<<dim3(16, 16), 256, 0, stream>>>(ab, o_sa, ob, Ee, Ee);
  ln_k<<<Bb, 256, 0, stream>>>(ob, ln_sa_s, ln_sa_b, dec, ds2, Ee);

  // --- cross-attention block ---
  ln_k<<<Bb, 256, 0, stream>>>(ds2, nullptr, ln_pre_ca_b, nullptr, x3, Ee);
  proj_k<<<dim3(16, 16), 256, 0, stream>>>(x3, q_ca, q2, Ee, Ee);
  attn_k<unsigned short><<<dim3(Bb, Hh), 64, 0, stream>>>(q2, ekb, evb, cb,
      nullptr, amask, Tt, (long)Tt * Ee, 0.125f);
  proj_k<<<dim3(16, 16), 256, 0, stream>>>(cb, o_ca, ob2, Ee, Ee);
  ln_k<<<Bb, 256, 0, stream>>>(ob2, ln_ca_s, ln_ca_b, ds2, ds3, Ee);

  // --- GLU block ---
  ln_k<<<Bb, 256, 0, stream>>>(ds3, nullptr, glu_ln0_b, nullptr, zb, Ee);
  proj_k<<<dim3(32, 16), 256, 0, stream>>>(zb, fc0, w0, Ee, Gg);
  proj_k<<<dim3(32, 16), 256, 0, stream>>>(zb, fc1, v1, Ee, Gg);
  gelu_mul_k<<<1024, 256, 0, stream>>>(w0, v1, wv, Bb * Gg);
  ln_k<<<Bb, 256, 0, stream>>>(wv, glu_ln1_s, glu_ln1_b, nullptr, wvn, Gg);
  proj_k<<<dim3(16, 32), 256, 0, stream>>>(wvn, fc2, z2, Gg, Ee);
  add_k<<<512, 256, 0, stream>>>(ds3, z2, out_dec, Bb * Ee);
}

// Round 3
// 1314.076 us; speedup vs baseline: 2.0117x; 1.1029x over previous
//
#include <hip/hip_runtime.h>

// Sizes fixed by the problem
#define Bb   64
#define Ee   2048
#define Tt   64
#define Gg   4096
#define Ii   256
#define Hh   32
#define Dd   64

using f32x4_t  = __attribute__((ext_vector_type(4))) float;
using bf16x8_t = __attribute__((ext_vector_type(8))) __bf16;

__device__ __forceinline__ unsigned short f2bf(float f) {
  unsigned u = __float_as_uint(f);
  u += 0x7FFFu + ((u >> 16) & 1u);          // RNE
  return (unsigned short)(u >> 16);
}
__device__ __forceinline__ float ldkv(float v) { return v; }
__device__ __forceinline__ float ldkv(unsigned short v) {
  return __uint_as_float(((unsigned)v) << 16);
}
__device__ __forceinline__ float gelu_f(float x) {
  return 0.5f * x * (1.0f + erff(x * 0.70710678118654752f));
}

template <typename T> __device__ __forceinline__ float4 ld4(const T* p);
template <> __device__ __forceinline__ float4 ld4<float>(const float* p) {
  return *(const float4*)p;
}
template <> __device__ __forceinline__ float4 ld4<unsigned short>(const unsigned short* p) {
  ushort4 u = *(const ushort4*)p;
  return make_float4(ldkv(u.x), ldkv(u.y), ldkv(u.z), ldkv(u.w));
}

// ---------------- state copy fused with KV-cache update at token_index ----------------
__global__ void copy_state_k(const float4* __restrict__ src, float4* __restrict__ dst,
                             const float4* __restrict__ kb, const float4* __restrict__ vb,
                             const int* __restrict__ tokp) {
  const int t = *tokp;
  const long n4 = (long)128 * Ii * (Ee / 4);
  long i = (long)blockIdx.x * blockDim.x + threadIdx.x;
  const long stride = (long)gridDim.x * blockDim.x;
  for (; i < n4; i += stride) {
    long row = i >> 9;                 // / (Ee/4)
    int tt = (int)(row & (Ii - 1));
    float4 v;
    if (tt == t) {                     // wave-uniform (rows are 512 float4 wide)
      int bh  = (int)(row >> 8);       // 0..127
      int col = (int)(i & 511);
      const float4* s = (bh < Bb) ? kb : vb;
      v = s[(long)(bh & (Bb - 1)) * (Ee / 4) + col];
    } else {
      v = src[i];
    }
    dst[i] = v;
  }
}

// ---------------- fp32 -> bf16 convert ----------------
__global__ void conv_bf16_k(const float4* __restrict__ in, unsigned short* __restrict__ out, long n4) {
  long i = (long)blockIdx.x * blockDim.x + threadIdx.x;
  long stride = (long)gridDim.x * blockDim.x;
  for (; i < n4; i += stride) {
    float4 f = in[i];
    ushort4 u;
    u.x = f2bf(f.x); u.y = f2bf(f.y); u.z = f2bf(f.z); u.w = f2bf(f.w);
    *(ushort4*)(out + i * 4) = u;
  }
}

// ---------------- transpose + convert: W[K][N] fp32 -> Wt[N][K] bf16 ----------------
__global__ void transpose_bf16_k(const float* __restrict__ W, unsigned short* __restrict__ Wt,
                                 int K, int N) {
  __shared__ unsigned short tile[64][65];
  int k0 = blockIdx.x * 64, n0 = blockIdx.y * 64;
  int c = threadIdx.x & 63;
  int r4 = threadIdx.x >> 6;
  #pragma unroll
  for (int i = 0; i < 16; i++) {
    int r = r4 + i * 4;
    tile[r][c] = f2bf(W[(long)(k0 + r) * N + n0 + c]);
  }
  __syncthreads();
  #pragma unroll
  for (int i = 0; i < 16; i++) {
    int r = r4 + i * 4;
    Wt[(long)(n0 + r) * K + k0 + c] = tile[c][r];
  }
}

// ---------------- layer norm: one-pass, 1 float4/thread, C = 4*blockDim ----------------
// GELU: p = gelu(in1)*in2 first.  HAS_SCALE: *scale.  HAS_RES: +res.  DUAL: also write out2.
template <bool GELU, bool HAS_SCALE, bool HAS_RES, bool DUAL>
__global__ void ln_k(const float4* __restrict__ in1, const float4* __restrict__ in2,
                     const float* __restrict__ scale, const float* __restrict__ bias,
                     const float4* __restrict__ res,
                     float4* __restrict__ out1, float4* __restrict__ out2) {
  const int row = blockIdx.x, tid = threadIdx.x;
  const int C = blockDim.x * 4;
  const long base = (long)row * blockDim.x + tid;

  float4 p = in1[base];
  if (GELU) {
    float4 vv = in2[base];
    p.x = gelu_f(p.x) * vv.x; p.y = gelu_f(p.y) * vv.y;
    p.z = gelu_f(p.z) * vv.z; p.w = gelu_f(p.w) * vv.w;
  }
  float s  = p.x + p.y + p.z + p.w;
  float s2 = p.x * p.x + p.y * p.y + p.z * p.z + p.w * p.w;

  __shared__ float rs[16], rs2[16];
  int lane = tid & 63, w = tid >> 6;
  #pragma unroll
  for (int o = 32; o; o >>= 1) { s += __shfl_down(s, o, 64); s2 += __shfl_down(s2, o, 64); }
  if (lane == 0) { rs[w] = s; rs2[w] = s2; }
  __syncthreads();
  if (tid == 0) {
    float ts = 0.f, ts2 = 0.f;
    int nw = blockDim.x >> 6;
    for (int i = 0; i < nw; i++) { ts += rs[i]; ts2 += rs2[i]; }
    float mu = ts / C;
    float var = ts2 / C - mu * mu;
    rs[0]  = mu;
    rs2[0] = rsqrtf(var + 1e-6f);
  }
  __syncthreads();
  const float mu = rs[0], rstd = rs2[0];

  float4 o;
  o.x = (p.x - mu) * rstd; o.y = (p.y - mu) * rstd;
  o.z = (p.z - mu) * rstd; o.w = (p.w - mu) * rstd;
  if (HAS_SCALE) {
    float4 sc4 = ((const float4*)scale)[tid];
    o.x *= sc4.x; o.y *= sc4.y; o.z *= sc4.z; o.w *= sc4.w;
  }
  float4 b4 = ((const float4*)bias)[tid];
  o.x += b4.x; o.y += b4.y; o.z += b4.z; o.w += b4.w;
  if (HAS_RES) {
    float4 r4 = res[base];
    o.x += r4.x; o.y += r4.y; o.z += r4.z; o.w += r4.w;
  }
  out1[base] = o;
  if (DUAL) out2[base] = o;
}

// ---------------- M=64 projection: Y[64][N] += X[64][K] @ W[K][N] ----------------
// block 256 = 32 n-quads x 8 m-groups(8 rows); grid (N/128, K/128); split-K atomics.
// NW = number of weight matrices sharing X (staged once).
template <int NW>
__global__ __launch_bounds__(256)
void proj_k(const float* __restrict__ X,
            const float* __restrict__ W0, const float* __restrict__ W1,
            const float* __restrict__ W2,
            float* __restrict__ Y0, float* __restrict__ Y1, float* __restrict__ Y2,
            int K, int N) {
  __shared__ float Xs[64 * 64];
  const int nq = threadIdx.x & 31;
  const int m0 = (threadIdx.x >> 5) * 8;
  const int n  = blockIdx.x * 128 + nq * 4;
  const int kbase = blockIdx.y * 128;

  f32x4_t acc[NW][8];
  #pragma unroll
  for (int wsel = 0; wsel < NW; wsel++)
    #pragma unroll
    for (int i = 0; i < 8; i++) acc[wsel][i] = (f32x4_t){0.f, 0.f, 0.f, 0.f};

  for (int k0 = kbase; k0 < kbase + 128; k0 += 64) {
    __syncthreads();
    #pragma unroll
    for (int j = 0; j < 16; j++) {
      int e = threadIdx.x + j * 256;        // e = m*64 + kk  (coalesced global read)
      Xs[e] = X[(long)(e >> 6) * K + k0 + (e & 63)];
    }
    __syncthreads();
    #pragma unroll 4
    for (int kk = 0; kk < 64; kk++) {
      const long wrow = (long)(k0 + kk) * N + n;
      f32x4_t w4[NW];
      w4[0] = *(const f32x4_t*)(W0 + wrow);
      if (NW > 1) w4[1] = *(const f32x4_t*)(W1 + wrow);
      if (NW > 2) w4[2] = *(const f32x4_t*)(W2 + wrow);
      #pragma unroll
      for (int i = 0; i < 8; i++) {
        float xm = Xs[(m0 + i) * 64 + kk];   // broadcast within 32-thread m-group
        #pragma unroll
        for (int wsel = 0; wsel < NW; wsel++) acc[wsel][i] += xm * w4[wsel];
      }
    }
  }
  float* Ys[3] = {Y0, Y1, Y2};
  #pragma unroll
  for (int wsel = 0; wsel < NW; wsel++) {
    #pragma unroll
    for (int i = 0; i < 8; i++) {
      float* yp = Ys[wsel] + (long)(m0 + i) * N + n;
      unsafeAtomicAdd(yp + 0, acc[wsel][i][0]);
      unsafeAtomicAdd(yp + 1, acc[wsel][i][1]);
      unsafeAtomicAdd(yp + 2, acc[wsel][i][2]);
      unsafeAtomicAdd(yp + 3, acc[wsel][i][3]);
    }
  }
}

// ---------------- attention (Q=1): one wave per (b,h) ----------------
// Scores bound by n (= token_index+1 for self, L for cross).  PV loop branch-free,
// unrolled x8 so 8 independent coalesced 256B loads stay in flight.
template <typename KVT>
__global__ void attn_k(const float* __restrict__ Q, const KVT* __restrict__ Kc,
                       const KVT* __restrict__ Vc, float* __restrict__ O,
                       const int* __restrict__ tokp, const int* __restrict__ maskp,
                       int L, long bstride, float scale) {
  const int b = blockIdx.x, h = blockIdx.y;
  const int lane = threadIdx.x;                 // 64 threads = 1 wave
  __shared__ float sc[256];
  const float* qp = Q + (long)b * Ee + h * Dd;  // wave-uniform -> scalar loads
  const int n = tokp ? (*tokp + 1) : L;

  float mx = -3.0e38f;
  for (int pos = lane; pos < n; pos += 64) {
    bool valid = maskp ? (maskp[(long)b * L + pos] != 0) : true;
    float s = -1.0e30f;
    if (valid) {
      const KVT* kr = Kc + (long)b * bstride + (long)pos * Ee + h * Dd;
      float acc = 0.f;
      #pragma unroll
      for (int j = 0; j < 16; j++) {
        float4 kv = ld4(kr + j * 4);
        acc += qp[j*4+0]*kv.x + qp[j*4+1]*kv.y + qp[j*4+2]*kv.z + qp[j*4+3]*kv.w;
      }
      s = acc * scale;
    }
    sc[pos] = s;
    mx = fmaxf(mx, s);
  }
  __syncthreads();
  #pragma unroll
  for (int o = 32; o; o >>= 1) mx = fmaxf(mx, __shfl_down(mx, o, 64));
  mx = __shfl(mx, 0, 64);

  float sum = 0.f;
  for (int pos = lane; pos < n; pos += 64) {
    float e = expf(sc[pos] - mx);
    sc[pos] = e;                                // masked positions -> exactly 0
    sum += e;
  }
  __syncthreads();
  #pragma unroll
  for (int o = 32; o; o >>= 1) sum += __shfl_down(sum, o, 64);
  sum = __shfl(sum, 0, 64);
  const float inv = 1.0f / sum;

  const KVT* vbase = Vc + (long)b * bstride + h * Dd + lane;
  float acc = 0.f;
  int pos = 0;
  for (; pos + 8 <= n; pos += 8) {
    #pragma unroll
    for (int u = 0; u < 8; u++)
      acc += sc[pos + u] * ldkv(vbase[(long)(pos + u) * Ee]);
  }
  for (; pos < n; pos++) acc += sc[pos] * ldkv(vbase[(long)pos * Ee]);
  O[(long)b * Ee + h * Dd + lane] = acc * inv;
}

// ---------------- bf16 MFMA GEMM: C[M][N] = A[M][K] @ B (Bt is [N][K]) ----------------
__global__ __launch_bounds__(256)
void gemm_bf16_k(const unsigned short* __restrict__ A, const unsigned short* __restrict__ Bt,
                 unsigned short* __restrict__ C, int M, int N, int K) {
  __shared__ unsigned short As[128 * 32];
  __shared__ unsigned short Bs[128 * 32];
  const int m0 = blockIdx.x * 128;
  const int n0 = blockIdx.y * 128;
  const int tid  = threadIdx.x;
  const int lane = tid & 63;
  const int wave = tid >> 6;
  const int wm = (wave >> 1) * 64;
  const int wn = (wave & 1) * 64;
  const int fr = lane & 15;
  const int fq = lane >> 4;

  const int r0 = tid >> 2;
  const int g0 = tid & 3;
  const int so1 = r0 * 32 + ((g0 ^ ((r0 >> 1) & 3)) * 8);   // XOR swizzle (2-way max)
  const int so2 = so1 + 64 * 32;

  f32x4_t acc[4][4];
  const f32x4_t zero = {0.f, 0.f, 0.f, 0.f};
  #pragma unroll
  for (int i = 0; i < 4; i++)
    #pragma unroll
    for (int j = 0; j < 4; j++) acc[i][j] = zero;

  const long aR1 = (long)(m0 + r0) * K;
  const long aR2 = (long)(m0 + r0 + 64) * K;
  const long bR1 = (long)(n0 + r0) * K;
  const long bR2 = (long)(n0 + r0 + 64) * K;

  for (int k0 = 0; k0 < K; k0 += 32) {
    uint4 va1 = *(const uint4*)(A  + aR1 + k0 + g0 * 8);
    uint4 va2 = *(const uint4*)(A  + aR2 + k0 + g0 * 8);
    uint4 vb1 = *(const uint4*)(Bt + bR1 + k0 + g0 * 8);
    uint4 vb2 = *(const uint4*)(Bt + bR2 + k0 + g0 * 8);
    __syncthreads();
    *(uint4*)(As + so1) = va1;
    *(uint4*)(As + so2) = va2;
    *(uint4*)(Bs + so1) = vb1;
    *(uint4*)(Bs + so2) = vb2;
    __syncthreads();

    bf16x8_t af[4], bb[4];
    #pragma unroll
    for (int ms = 0; ms < 4; ms++) {
      int row = wm + ms * 16 + fr;
      af[ms] = __builtin_bit_cast(bf16x8_t,
               *(const uint4*)(As + row * 32 + ((fq ^ ((row >> 1) & 3)) * 8)));
    }
    #pragma unroll
    for (int ns = 0; ns < 4; ns++) {
      int row = wn + ns * 16 + fr;
      bb[ns] = __builtin_bit_cast(bf16x8_t,
               *(const uint4*)(Bs + row * 32 + ((fq ^ ((row >> 1) & 3)) * 8)));
    }
    #pragma unroll
    for (int ms = 0; ms < 4; ms++)
      #pragma unroll
      for (int ns = 0; ns < 4; ns++)
        acc[ms][ns] = __builtin_amdgcn_mfma_f32_16x16x32_bf16(af[ms], bb[ns], acc[ms][ns], 0, 0, 0);
  }

  #pragma unroll
  for (int ms = 0; ms < 4; ms++) {
    #pragma unroll
    for (int ns = 0; ns < 4; ns++) {
      int row = m0 + wm + ms * 16 + fq * 4;
      int col = n0 + wn + ns * 16 + fr;
      #pragma unroll
      for (int r = 0; r < 4; r++)
        C[(long)(row + r) * N + col] = f2bf(acc[ms][ns][r]);
    }
  }
}

extern "C" void kernel_launch(void* const* d_in, const int* in_sizes, int n_in,
                              void* d_out, int out_size, void* d_ws, size_t ws_size,
                              hipStream_t stream) {
  const float* dec    = (const float*)d_in[0];
  const float* enc    = (const float*)d_in[1];
  const float* astate = (const float*)d_in[2];
  const int*   amask  = (const int*)d_in[3];
  const int*   tokp   = (const int*)d_in[4];
  const float* ln_pre_sa_b = (const float*)d_in[5];
  const float* q_sa = (const float*)d_in[6];
  const float* k_sa = (const float*)d_in[7];
  const float* v_sa = (const float*)d_in[8];
  const float* o_sa = (const float*)d_in[9];
  const float* ln_sa_s = (const float*)d_in[10];
  const float* ln_sa_b = (const float*)d_in[11];
  const float* ln_pre_ca_b = (const float*)d_in[12];
  const float* q_ca = (const float*)d_in[13];
  const float* k_ca = (const float*)d_in[14];
  const float* v_ca = (const float*)d_in[15];
  const float* o_ca = (const float*)d_in[16];
  const float* ln_ca_s = (const float*)d_in[17];
  const float* ln_ca_b = (const float*)d_in[18];
  const float* glu_ln0_b = (const float*)d_in[19];
  const float* fc0 = (const float*)d_in[20];
  const float* fc1 = (const float*)d_in[21];
  const float* glu_ln1_s = (const float*)d_in[22];
  const float* glu_ln1_b = (const float*)d_in[23];
  const float* fc2 = (const float*)d_in[24];

  float* out_dec   = (float*)d_out;
  float* out_state = out_dec + (long)Bb * Ee;

  // ---- workspace carve ----
  // zero zone first (atomic-accumulated projection outputs)
  float* qb  = (float*)d_ws;            // 64*2048
  float* kb  = qb  + 131072;
  float* vb  = kb  + 131072;
  float* ob  = vb  + 131072;
  float* q2  = ob  + 131072;
  float* ob2 = q2  + 131072;
  float* w0  = ob2 + 131072;            // 64*4096
  float* v1  = w0  + 262144;
  size_t zero_bytes = (6L * 131072 + 2L * 262144) * 4;   // 5,242,880 B
  float* x1  = v1  + 262144;
  float* ab  = x1  + 131072;
  float* ds2 = ab  + 131072;
  float* x3  = ds2 + 131072;
  float* cb  = x3  + 131072;
  float* ds3 = cb  + 131072;
  float* zb  = ds3 + 131072;
  float* wvn = zb  + 131072;            // 64*4096
  unsigned short* ebf = (unsigned short*)(wvn + 262144);  // 4096*2048 bf16
  unsigned short* kt  = ebf + 8388608;                    // 2048*2048 bf16 (transposed)
  unsigned short* vt  = kt  + 4194304;
  unsigned short* ekb = vt  + 4194304;                    // 4096*2048 bf16
  unsigned short* evb = ekb + 8388608;

  hipMemsetAsync(d_ws, 0, zero_bytes, stream);

  // bf16 conversions + the two big cross-attn GEMMs (M=4096, N=2048, K=2048)
  conv_bf16_k<<<2048, 256, 0, stream>>>((const float4*)enc, ebf, (long)Bb * Tt * Ee / 4);
  transpose_bf16_k<<<dim3(32, 32), 256, 0, stream>>>(k_ca, kt, Ee, Ee);
  transpose_bf16_k<<<dim3(32, 32), 256, 0, stream>>>(v_ca, vt, Ee, Ee);
  gemm_bf16_k<<<dim3(32, 16), 256, 0, stream>>>(ebf, kt, ekb, 4096, Ee, Ee);
  gemm_bf16_k<<<dim3(32, 16), 256, 0, stream>>>(ebf, vt, evb, 4096, Ee, Ee);

  // --- self-attention block ---
  ln_k<false,false,false,false><<<Bb, 512, 0, stream>>>(
      (const float4*)dec, nullptr, nullptr, ln_pre_sa_b, nullptr, (float4*)x1, nullptr);
  proj_k<3><<<dim3(16, 16), 256, 0, stream>>>(x1, q_sa, k_sa, v_sa, qb, kb, vb, Ee, Ee);
  copy_state_k<<<4096, 256, 0, stream>>>((const float4*)astate, (float4*)out_state,
                                         (const float4*)kb, (const float4*)vb, tokp);
  attn_k<float><<<dim3(Bb, Hh), 64, 0, stream>>>(qb, out_state,
      out_state + (long)Bb * Ii * Ee, ab, tokp, nullptr, Ii, (long)Ii * Ee, 0.125f);
  proj_k<1><<<dim3(16, 16), 256, 0, stream>>>(ab, o_sa, nullptr, nullptr, ob, nullptr, nullptr, Ee, Ee);
  ln_k<false,true,true,false><<<Bb, 512, 0, stream>>>(
      (const float4*)ob, nullptr, ln_sa_s, ln_sa_b, (const float4*)dec, (float4*)ds2, nullptr);

  // --- cross-attention block ---
  ln_k<false,false,false,false><<<Bb, 512, 0, stream>>>(
      (const float4*)ds2, nullptr, nullptr, ln_pre_ca_b, nullptr, (float4*)x3, nullptr);
  proj_k<1><<<dim3(16, 16), 256, 0, stream>>>(x3, q_ca, nullptr, nullptr, q2, nullptr, nullptr, Ee, Ee);
  attn_k<unsigned short><<<dim3(Bb, Hh), 64, 0, stream>>>(q2, ekb, evb, cb,
      nullptr, amask, Tt, (long)Tt * Ee, 0.125f);
  proj_k<1><<<dim3(16, 16), 256, 0, stream>>>(cb, o_ca, nullptr, nullptr, ob2, nullptr, nullptr, Ee, Ee);
  // dual-output: ds3 (for GLU) and out_dec (residual base for fc2's atomic add)
  ln_k<false,true,true,true><<<Bb, 512, 0, stream>>>(
      (const float4*)ob2, nullptr, ln_ca_s, ln_ca_b, (const float4*)ds2,
      (float4*)ds3, (float4*)out_dec);

  // --- GLU block ---
  ln_k<false,false,false,false><<<Bb, 512, 0, stream>>>(
      (const float4*)ds3, nullptr, nullptr, glu_ln0_b, nullptr, (float4*)zb, nullptr);
  proj_k<2><<<dim3(32, 16), 256, 0, stream>>>(zb, fc0, fc1, nullptr, w0, v1, nullptr, Ee, Gg);
  ln_k<true,true,false,false><<<Bb, 1024, 0, stream>>>(
      (const float4*)w0, (const float4*)v1, glu_ln1_s, glu_ln1_b, nullptr, (float4*)wvn, nullptr);
  proj_k<1><<<dim3(16, 32), 256, 0, stream>>>(wvn, fc2, nullptr, nullptr, out_dec, nullptr, nullptr, Gg, Ee);
}

// Round 4
// 1067.293 us; speedup vs baseline: 2.4768x; 1.2312x over previous
//
#include <hip/hip_runtime.h>

// Sizes fixed by the problem
#define Bb   64
#define Ee   2048
#define Tt   64
#define Gg   4096
#define Ii   256
#define Hh   32
#define Dd   64

using f32x4_t  = __attribute__((ext_vector_type(4))) float;
using bf16x8_t = __attribute__((ext_vector_type(8))) __bf16;

__device__ __forceinline__ unsigned short f2bf(float f) {
  unsigned u = __float_as_uint(f);
  u += 0x7FFFu + ((u >> 16) & 1u);          // RNE
  return (unsigned short)(u >> 16);
}
__device__ __forceinline__ float ldkv(float v) { return v; }
__device__ __forceinline__ float ldkv(unsigned short v) {
  return __uint_as_float(((unsigned)v) << 16);
}
__device__ __forceinline__ float gelu_f(float x) {
  return 0.5f * x * (1.0f + erff(x * 0.70710678118654752f));
}

template <typename T> __device__ __forceinline__ float4 ld4(const T* p);
template <> __device__ __forceinline__ float4 ld4<float>(const float* p) {
  return *(const float4*)p;
}
template <> __device__ __forceinline__ float4 ld4<unsigned short>(const unsigned short* p) {
  ushort4 u = *(const ushort4*)p;
  return make_float4(ldkv(u.x), ldkv(u.y), ldkv(u.z), ldkv(u.w));
}

// ---------------- state copy fused with KV-cache update at token_index ----------------
__global__ void copy_state_k(const float4* __restrict__ src, float4* __restrict__ dst,
                             const float4* __restrict__ kb, const float4* __restrict__ vb,
                             const int* __restrict__ tokp) {
  const int t = *tokp;
  const long n4 = (long)128 * Ii * (Ee / 4);
  long i = (long)blockIdx.x * blockDim.x + threadIdx.x;
  const long stride = (long)gridDim.x * blockDim.x;
  for (; i < n4; i += stride) {
    long row = i >> 9;                 // / (Ee/4)
    int tt = (int)(row & (Ii - 1));
    float4 v;
    if (tt == t) {                     // wave-uniform (rows are 512 float4 wide)
      int bh  = (int)(row >> 8);       // 0..127
      int col = (int)(i & 511);
      const float4* s = (bh < Bb) ? kb : vb;
      v = s[(long)(bh & (Bb - 1)) * (Ee / 4) + col];
    } else {
      v = src[i];
    }
    dst[i] = v;
  }
}

// ---------------- fp32 -> bf16 convert ----------------
__global__ void conv_bf16_k(const float4* __restrict__ in, unsigned short* __restrict__ out, long n4) {
  long i = (long)blockIdx.x * blockDim.x + threadIdx.x;
  long stride = (long)gridDim.x * blockDim.x;
  for (; i < n4; i += stride) {
    float4 f = in[i];
    ushort4 u;
    u.x = f2bf(f.x); u.y = f2bf(f.y); u.z = f2bf(f.z); u.w = f2bf(f.w);
    *(ushort4*)(out + i * 4) = u;
  }
}

// ---------------- transpose + convert: W[K][N] fp32 -> Wt[N][K] bf16 ----------------
__global__ void transpose_bf16_k(const float* __restrict__ W, unsigned short* __restrict__ Wt,
                                 int K, int N) {
  __shared__ unsigned short tile[64][65];
  int k0 = blockIdx.x * 64, n0 = blockIdx.y * 64;
  int c = threadIdx.x & 63;
  int r4 = threadIdx.x >> 6;
  #pragma unroll
  for (int i = 0; i < 16; i++) {
    int r = r4 + i * 4;
    tile[r][c] = f2bf(W[(long)(k0 + r) * N + n0 + c]);
  }
  __syncthreads();
  #pragma unroll
  for (int i = 0; i < 16; i++) {
    int r = r4 + i * 4;
    Wt[(long)(n0 + r) * K + k0 + c] = tile[c][r];
  }
}

// ---------------- layer norm: one-pass, 1 float4/thread, C = 4*blockDim ----------------
template <bool GELU, bool HAS_SCALE, bool HAS_RES, bool DUAL>
__global__ void ln_k(const float4* __restrict__ in1, const float4* __restrict__ in2,
                     const float* __restrict__ scale, const float* __restrict__ bias,
                     const float4* __restrict__ res,
                     float4* __restrict__ out1, float4* __restrict__ out2) {
  const int row = blockIdx.x, tid = threadIdx.x;
  const int C = blockDim.x * 4;
  const long base = (long)row * blockDim.x + tid;

  float4 p = in1[base];
  if (GELU) {
    float4 vv = in2[base];
    p.x = gelu_f(p.x) * vv.x; p.y = gelu_f(p.y) * vv.y;
    p.z = gelu_f(p.z) * vv.z; p.w = gelu_f(p.w) * vv.w;
  }
  float s  = p.x + p.y + p.z + p.w;
  float s2 = p.x * p.x + p.y * p.y + p.z * p.z + p.w * p.w;

  __shared__ float rs[16], rs2[16];
  int lane = tid & 63, w = tid >> 6;
  #pragma unroll
  for (int o = 32; o; o >>= 1) { s += __shfl_down(s, o, 64); s2 += __shfl_down(s2, o, 64); }
  if (lane == 0) { rs[w] = s; rs2[w] = s2; }
  __syncthreads();
  if (tid == 0) {
    float ts = 0.f, ts2 = 0.f;
    int nw = blockDim.x >> 6;
    for (int i = 0; i < nw; i++) { ts += rs[i]; ts2 += rs2[i]; }
    float mu = ts / C;
    float var = ts2 / C - mu * mu;
    rs[0]  = mu;
    rs2[0] = rsqrtf(var + 1e-6f);
  }
  __syncthreads();
  const float mu = rs[0], rstd = rs2[0];

  float4 o;
  o.x = (p.x - mu) * rstd; o.y = (p.y - mu) * rstd;
  o.z = (p.z - mu) * rstd; o.w = (p.w - mu) * rstd;
  if (HAS_SCALE) {
    float4 sc4 = ((const float4*)scale)[tid];
    o.x *= sc4.x; o.y *= sc4.y; o.z *= sc4.z; o.w *= sc4.w;
  }
  float4 b4 = ((const float4*)bias)[tid];
  o.x += b4.x; o.y += b4.y; o.z += b4.z; o.w += b4.w;
  if (HAS_RES) {
    float4 r4 = res[base];
    o.x += r4.x; o.y += r4.y; o.z += r4.z; o.w += r4.w;
  }
  out1[base] = o;
  if (DUAL) out2[base] = o;
}

// ---------------- M=64 projection, atomic-free split-K ----------------
// block 256 = 32 n-quads x 8 m-groups(8 rows); grid (N/128, K/128).
// Each block writes its K-chunk partial to arena P at [kblk][w][m][n] with plain
// coalesced float4 stores (round-3 lesson: device-scope atomicAdd = memory-side
// RMW on gfx950 -> 128 MiB HBM writes per dispatch, 85x amplification).
template <int NW>
__global__ __launch_bounds__(256)
void proj_k(const float* __restrict__ X,
            const float* __restrict__ W0, const float* __restrict__ W1,
            const float* __restrict__ W2,
            float* __restrict__ P, int K, int N) {
  __shared__ float Xs[64 * 64];
  const int nq = threadIdx.x & 31;
  const int m0 = (threadIdx.x >> 5) * 8;
  const int n  = blockIdx.x * 128 + nq * 4;
  const int kbase = blockIdx.y * 128;

  f32x4_t acc[NW][8];
  #pragma unroll
  for (int wsel = 0; wsel < NW; wsel++)
    #pragma unroll
    for (int i = 0; i < 8; i++) acc[wsel][i] = (f32x4_t){0.f, 0.f, 0.f, 0.f};

  for (int k0 = kbase; k0 < kbase + 128; k0 += 64) {
    __syncthreads();
    #pragma unroll
    for (int j = 0; j < 16; j++) {
      int e = threadIdx.x + j * 256;        // e = m*64 + kk  (coalesced global read)
      Xs[e] = X[(long)(e >> 6) * K + k0 + (e & 63)];
    }
    __syncthreads();
    #pragma unroll 4
    for (int kk = 0; kk < 64; kk++) {
      const long wrow = (long)(k0 + kk) * N + n;
      f32x4_t w4[NW];
      w4[0] = *(const f32x4_t*)(W0 + wrow);
      if (NW > 1) w4[1] = *(const f32x4_t*)(W1 + wrow);
      if (NW > 2) w4[2] = *(const f32x4_t*)(W2 + wrow);
      #pragma unroll
      for (int i = 0; i < 8; i++) {
        float xm = Xs[(m0 + i) * 64 + kk];   // 2-way LDS broadcast (free)
        #pragma unroll
        for (int wsel = 0; wsel < NW; wsel++) acc[wsel][i] += xm * w4[wsel];
      }
    }
  }
  float* base = P + (long)blockIdx.y * ((long)NW * 64 * N);
  #pragma unroll
  for (int wsel = 0; wsel < NW; wsel++) {
    #pragma unroll
    for (int i = 0; i < 8; i++) {
      *(f32x4_t*)(base + ((long)wsel * 64 + m0 + i) * N + n) = acc[wsel][i];
    }
  }
}

// ---------------- split-K reduce: Y[e] (+)= sum_k P[k*n4 + e] ----------------
template <bool ACCUM>
__global__ void reduce_k(const float4* __restrict__ P, float4* __restrict__ Y,
                         int KB, long n4) {
  long i = (long)blockIdx.x * blockDim.x + threadIdx.x;
  if (i >= n4) return;
  float4 s = ACCUM ? Y[i] : make_float4(0.f, 0.f, 0.f, 0.f);
  for (int k = 0; k < KB; k++) {
    float4 p = P[(long)k * n4 + i];
    s.x += p.x; s.y += p.y; s.z += p.z; s.w += p.w;
  }
  Y[i] = s;
}

// ---------------- attention (Q=1): one wave per (b,h) ----------------
template <typename KVT>
__global__ void attn_k(const float* __restrict__ Q, const KVT* __restrict__ Kc,
                       const KVT* __restrict__ Vc, float* __restrict__ O,
                       const int* __restrict__ tokp, const int* __restrict__ maskp,
                       int L, long bstride, float scale) {
  const int b = blockIdx.x, h = blockIdx.y;
  const int lane = threadIdx.x;                 // 64 threads = 1 wave
  __shared__ float sc[256];
  const float* qp = Q + (long)b * Ee + h * Dd;  // wave-uniform -> scalar loads
  const int n = tokp ? (*tokp + 1) : L;

  float mx = -3.0e38f;
  for (int pos = lane; pos < n; pos += 64) {
    bool valid = maskp ? (maskp[(long)b * L + pos] != 0) : true;
    float s = -1.0e30f;
    if (valid) {
      const KVT* kr = Kc + (long)b * bstride + (long)pos * Ee + h * Dd;
      float acc = 0.f;
      #pragma unroll
      for (int j = 0; j < 16; j++) {
        float4 kv = ld4(kr + j * 4);
        acc += qp[j*4+0]*kv.x + qp[j*4+1]*kv.y + qp[j*4+2]*kv.z + qp[j*4+3]*kv.w;
      }
      s = acc * scale;
    }
    sc[pos] = s;
    mx = fmaxf(mx, s);
  }
  __syncthreads();
  #pragma unroll
  for (int o = 32; o; o >>= 1) mx = fmaxf(mx, __shfl_down(mx, o, 64));
  mx = __shfl(mx, 0, 64);

  float sum = 0.f;
  for (int pos = lane; pos < n; pos += 64) {
    float e = expf(sc[pos] - mx);
    sc[pos] = e;                                // masked positions -> exactly 0
    sum += e;
  }
  __syncthreads();
  #pragma unroll
  for (int o = 32; o; o >>= 1) sum += __shfl_down(sum, o, 64);
  sum = __shfl(sum, 0, 64);
  const float inv = 1.0f / sum;

  const KVT* vbase = Vc + (long)b * bstride + h * Dd + lane;
  float acc = 0.f;
  int pos = 0;
  for (; pos + 8 <= n; pos += 8) {
    #pragma unroll
    for (int u = 0; u < 8; u++)
      acc += sc[pos + u] * ldkv(vbase[(long)(pos + u) * Ee]);
  }
  for (; pos < n; pos++) acc += sc[pos] * ldkv(vbase[(long)pos * Ee]);
  O[(long)b * Ee + h * Dd + lane] = acc * inv;
}

// ---------------- bf16 MFMA GEMM: C[M][N] = A[M][K] @ B (Bt is [N][K]) ----------------
__global__ __launch_bounds__(256)
void gemm_bf16_k(const unsigned short* __restrict__ A, const unsigned short* __restrict__ Bt,
                 unsigned short* __restrict__ C, int M, int N, int K) {
  __shared__ unsigned short As[128 * 32];
  __shared__ unsigned short Bs[128 * 32];
  const int m0 = blockIdx.x * 128;
  const int n0 = blockIdx.y * 128;
  const int tid  = threadIdx.x;
  const int lane = tid & 63;
  const int wave = tid >> 6;
  const int wm = (wave >> 1) * 64;
  const int wn = (wave & 1) * 64;
  const int fr = lane & 15;
  const int fq = lane >> 4;

  const int r0 = tid >> 2;
  const int g0 = tid & 3;
  const int so1 = r0 * 32 + ((g0 ^ ((r0 >> 1) & 3)) * 8);   // XOR swizzle (2-way max)
  const int so2 = so1 + 64 * 32;

  f32x4_t acc[4][4];
  const f32x4_t zero = {0.f, 0.f, 0.f, 0.f};
  #pragma unroll
  for (int i = 0; i < 4; i++)
    #pragma unroll
    for (int j = 0; j < 4; j++) acc[i][j] = zero;

  const long aR1 = (long)(m0 + r0) * K;
  const long aR2 = (long)(m0 + r0 + 64) * K;
  const long bR1 = (long)(n0 + r0) * K;
  const long bR2 = (long)(n0 + r0 + 64) * K;

  for (int k0 = 0; k0 < K; k0 += 32) {
    uint4 va1 = *(const uint4*)(A  + aR1 + k0 + g0 * 8);
    uint4 va2 = *(const uint4*)(A  + aR2 + k0 + g0 * 8);
    uint4 vb1 = *(const uint4*)(Bt + bR1 + k0 + g0 * 8);
    uint4 vb2 = *(const uint4*)(Bt + bR2 + k0 + g0 * 8);
    __syncthreads();
    *(uint4*)(As + so1) = va1;
    *(uint4*)(As + so2) = va2;
    *(uint4*)(Bs + so1) = vb1;
    *(uint4*)(Bs + so2) = vb2;
    __syncthreads();

    bf16x8_t af[4], bb[4];
    #pragma unroll
    for (int ms = 0; ms < 4; ms++) {
      int row = wm + ms * 16 + fr;
      af[ms] = __builtin_bit_cast(bf16x8_t,
               *(const uint4*)(As + row * 32 + ((fq ^ ((row >> 1) & 3)) * 8)));
    }
    #pragma unroll
    for (int ns = 0; ns < 4; ns++) {
      int row = wn + ns * 16 + fr;
      bb[ns] = __builtin_bit_cast(bf16x8_t,
               *(const uint4*)(Bs + row * 32 + ((fq ^ ((row >> 1) & 3)) * 8)));
    }
    #pragma unroll
    for (int ms = 0; ms < 4; ms++)
      #pragma unroll
      for (int ns = 0; ns < 4; ns++)
        acc[ms][ns] = __builtin_amdgcn_mfma_f32_16x16x32_bf16(af[ms], bb[ns], acc[ms][ns], 0, 0, 0);
  }

  #pragma unroll
  for (int ms = 0; ms < 4; ms++) {
    #pragma unroll
    for (int ns = 0; ns < 4; ns++) {
      int row = m0 + wm + ms * 16 + fq * 4;
      int col = n0 + wn + ns * 16 + fr;
      #pragma unroll
      for (int r = 0; r < 4; r++)
        C[(long)(row + r) * N + col] = f2bf(acc[ms][ns][r]);
    }
  }
}

extern "C" void kernel_launch(void* const* d_in, const int* in_sizes, int n_in,
                              void* d_out, int out_size, void* d_ws, size_t ws_size,
                              hipStream_t stream) {
  const float* dec    = (const float*)d_in[0];
  const float* enc    = (const float*)d_in[1];
  const float* astate = (const float*)d_in[2];
  const int*   amask  = (const int*)d_in[3];
  const int*   tokp   = (const int*)d_in[4];
  const float* ln_pre_sa_b = (const float*)d_in[5];
  const float* q_sa = (const float*)d_in[6];
  const float* k_sa = (const float*)d_in[7];
  const float* v_sa = (const float*)d_in[8];
  const float* o_sa = (const float*)d_in[9];
  const float* ln_sa_s = (const float*)d_in[10];
  const float* ln_sa_b = (const float*)d_in[11];
  const float* ln_pre_ca_b = (const float*)d_in[12];
  const float* q_ca = (const float*)d_in[13];
  const float* k_ca = (const float*)d_in[14];
  const float* v_ca = (const float*)d_in[15];
  const float* o_ca = (const float*)d_in[16];
  const float* ln_ca_s = (const float*)d_in[17];
  const float* ln_ca_b = (const float*)d_in[18];
  const float* glu_ln0_b = (const float*)d_in[19];
  const float* fc0 = (const float*)d_in[20];
  const float* fc1 = (const float*)d_in[21];
  const float* glu_ln1_s = (const float*)d_in[22];
  const float* glu_ln1_b = (const float*)d_in[23];
  const float* fc2 = (const float*)d_in[24];

  float* out_dec   = (float*)d_out;
  float* out_state = out_dec + (long)Bb * Ee;

  // ---- workspace carve ----
  float* qb  = (float*)d_ws;            // qb,kb,vb contiguous (one reduce)
  float* kb  = qb  + 131072;
  float* vb  = kb  + 131072;
  float* ob  = vb  + 131072;
  float* q2  = ob  + 131072;
  float* ob2 = q2  + 131072;
  float* w0  = ob2 + 131072;            // w0,v1 contiguous (one reduce)
  float* v1  = w0  + 262144;
  float* x1  = v1  + 262144;
  float* ab  = x1  + 131072;
  float* ds2 = ab  + 131072;
  float* x3  = ds2 + 131072;
  float* cb  = x3  + 131072;
  float* ds3 = cb  + 131072;
  float* zb  = ds3 + 131072;
  float* wvn = zb  + 131072;            // 64*4096
  unsigned short* ebf = (unsigned short*)(wvn + 262144);  // 4096*2048 bf16
  unsigned short* kt  = ebf + 8388608;                    // 2048*2048 bf16 (transposed)
  unsigned short* vt  = kt  + 4194304;
  unsigned short* ekb = vt  + 4194304;                    // 4096*2048 bf16
  unsigned short* evb = ekb + 8388608;
  float* arena = (float*)(evb + 8388608);                 // split-K partials, 33.6 MB max

  // bf16 conversions + the two big cross-attn GEMMs (M=4096, N=2048, K=2048)
  conv_bf16_k<<<2048, 256, 0, stream>>>((const float4*)enc, ebf, (long)Bb * Tt * Ee / 4);
  transpose_bf16_k<<<dim3(32, 32), 256, 0, stream>>>(k_ca, kt, Ee, Ee);
  transpose_bf16_k<<<dim3(32, 32), 256, 0, stream>>>(v_ca, vt, Ee, Ee);
  gemm_bf16_k<<<dim3(32, 16), 256, 0, stream>>>(ebf, kt, ekb, 4096, Ee, Ee);
  gemm_bf16_k<<<dim3(32, 16), 256, 0, stream>>>(ebf, vt, evb, 4096, Ee, Ee);

  // --- self-attention block ---
  ln_k<false,false,false,false><<<Bb, 512, 0, stream>>>(
      (const float4*)dec, nullptr, nullptr, ln_pre_sa_b, nullptr, (float4*)x1, nullptr);
  proj_k<3><<<dim3(16, 16), 256, 0, stream>>>(x1, q_sa, k_sa, v_sa, arena, Ee, Ee);
  reduce_k<false><<<384, 256, 0, stream>>>((const float4*)arena, (float4*)qb, 16, 98304);
  copy_state_k<<<4096, 256, 0, stream>>>((const float4*)astate, (float4*)out_state,
                                         (const float4*)kb, (const float4*)vb, tokp);
  attn_k<float><<<dim3(Bb, Hh), 64, 0, stream>>>(qb, out_state,
      out_state + (long)Bb * Ii * Ee, ab, tokp, nullptr, Ii, (long)Ii * Ee, 0.125f);
  proj_k<1><<<dim3(16, 16), 256, 0, stream>>>(ab, o_sa, nullptr, nullptr, arena, Ee, Ee);
  reduce_k<false><<<128, 256, 0, stream>>>((const float4*)arena, (float4*)ob, 16, 32768);
  ln_k<false,true,true,false><<<Bb, 512, 0, stream>>>(
      (const float4*)ob, nullptr, ln_sa_s, ln_sa_b, (const float4*)dec, (float4*)ds2, nullptr);

  // --- cross-attention block ---
  ln_k<false,false,false,false><<<Bb, 512, 0, stream>>>(
      (const float4*)ds2, nullptr, nullptr, ln_pre_ca_b, nullptr, (float4*)x3, nullptr);
  proj_k<1><<<dim3(16, 16), 256, 0, stream>>>(x3, q_ca, nullptr, nullptr, arena, Ee, Ee);
  reduce_k<false><<<128, 256, 0, stream>>>((const float4*)arena, (float4*)q2, 16, 32768);
  attn_k<unsigned short><<<dim3(Bb, Hh), 64, 0, stream>>>(q2, ekb, evb, cb,
      nullptr, amask, Tt, (long)Tt * Ee, 0.125f);
  proj_k<1><<<dim3(16, 16), 256, 0, stream>>>(cb, o_ca, nullptr, nullptr, arena, Ee, Ee);
  reduce_k<false><<<128, 256, 0, stream>>>((const float4*)arena, (float4*)ob2, 16, 32768);
  // dual-output: ds3 (for GLU) and out_dec (residual base for fc2's reduce-accumulate)
  ln_k<false,true,true,true><<<Bb, 512, 0, stream>>>(
      (const float4*)ob2, nullptr, ln_ca_s, ln_ca_b, (const float4*)ds2,
      (float4*)ds3, (float4*)out_dec);

  // --- GLU block ---
  ln_k<false,false,false,false><<<Bb, 512, 0, stream>>>(
      (const float4*)ds3, nullptr, nullptr, glu_ln0_b, nullptr, (float4*)zb, nullptr);
  proj_k<2><<<dim3(32, 16), 256, 0, stream>>>(zb, fc0, fc1, nullptr, arena, Ee, Gg);
  reduce_k<false><<<512, 256, 0, stream>>>((const float4*)arena, (float4*)w0, 16, 131072);
  ln_k<true,true,false,false><<<Bb, 1024, 0, stream>>>(
      (const float4*)w0, (const float4*)v1, glu_ln1_s, glu_ln1_b, nullptr, (float4*)wvn, nullptr);
  proj_k<1><<<dim3(16, 32), 256, 0, stream>>>(wvn, fc2, nullptr, nullptr, arena, Gg, Ee);
  reduce_k<true><<<128, 256, 0, stream>>>((const float4*)arena, (float4*)out_dec, 32, 32768);
}